// Round 3
// baseline (1117.840 us; speedup 1.0000x reference)
//
#include <hip/hip_runtime.h>
#include <hip/hip_bf16.h>

// attention_84464826843938: additive-attention pooling, MI355X (gfx950)
//
// R3: K-split score GEMM for occupancy (R2: 2 blocks/CU, Occ 39.6%).
//  K1 pack_w_k : W_w fp32 -> bf16 MFMA B-fragment order (ws, 2 MB)
//  K2 prep_p_k : p'[b,d] = prev@W2_w + W2_b + W_b
//  K3 score_k  : grid = B*2(DIM half)*4(K-split 512) = 2048 blocks, 512 thr.
//                8 blocks/CU -> wave cap 32/CU (VGPR 44, LDS 18KB). Zero
//                B-duplication wave layout (wave = 64 rows x 32 cols).
//  K4 wsum_k   : softmax over 8 partials + q = sum_r aw*features,
//                grid = B*8 = 2048 blocks, 256 thr, L3-hot streaming.

#define B_ 256
#define R_ 64
#define F_ 2048
#define H_ 512
#define DIM_ 512

typedef short bf16x8 __attribute__((ext_vector_type(8)));
typedef float f32x4 __attribute__((ext_vector_type(4)));

__device__ __forceinline__ ushort f2bf(float x) {
  __hip_bfloat16 h = __float2bfloat16(x);
  return __builtin_bit_cast(ushort, h);
}

__device__ __forceinline__ uint4 pack8(float4 x, float4 y) {
  uint4 r;
  r.x = (uint)f2bf(x.x) | ((uint)f2bf(x.y) << 16);
  r.y = (uint)f2bf(x.z) | ((uint)f2bf(x.w) << 16);
  r.z = (uint)f2bf(y.x) | ((uint)f2bf(y.y) << 16);
  r.w = (uint)f2bf(y.z) | ((uint)f2bf(y.w) << 16);
  return r;
}

// wpack[((kt32*32 + ctg)*64 + g*16 + c)*8 + i] = bf16(W_w[kt32*32 + g*8 + i][ctg*16 + c])
__global__ void pack_w_k(const float* __restrict__ Ww, ushort* __restrict__ wpack) {
  int idx = blockIdx.x * 256 + threadIdx.x;
  float v = Ww[idx];
  int k = idx >> 9;
  int d = idx & 511;
  int kt = k >> 5, kr = k & 31;
  int g = kr >> 3, i = kr & 7;
  int ctg = d >> 4, c = d & 15;
  size_t dst = ((size_t)((kt * 32 + ctg) * 64 + g * 16 + c)) * 8 + (size_t)i;
  wpack[dst] = f2bf(v);
}

// p'[b][d] = prev[b]@W2_w[:,d] + W2_b[d] + W_b[d]; grid = 32 bgroups x 8 dslices
__global__ __launch_bounds__(256) void prep_p_k(const float* __restrict__ prev,
                                                const float* __restrict__ W2w,
                                                const float* __restrict__ W2b,
                                                const float* __restrict__ Wb,
                                                float* __restrict__ pprime) {
  __shared__ float lprev[8][H_];
  int bg = blockIdx.x >> 3;
  int d0 = (blockIdx.x & 7) * 64;
  int t = threadIdx.x;
  const float4* src = reinterpret_cast<const float4*>(prev + (size_t)bg * 8 * H_);
  float4* dst = reinterpret_cast<float4*>(&lprev[0][0]);
  for (int i = t; i < 8 * H_ / 4; i += 256) dst[i] = src[i];
  __syncthreads();
  int d = d0 + (t & 63);
  int bq = t >> 6;
  float a0 = 0.f, a1 = 0.f;
  #pragma unroll 8
  for (int h = 0; h < H_; ++h) {
    float wv = W2w[h * DIM_ + d];
    a0 += lprev[bq][h] * wv;
    a1 += lprev[bq + 4][h] * wv;
  }
  float bias = W2b[d] + Wb[d];
  pprime[(size_t)(bg * 8 + bq) * DIM_ + d] = a0 + bias;
  pprime[(size_t)(bg * 8 + bq + 4) * DIM_ + d] = a1 + bias;
}

__device__ __forceinline__ float fast_tanh(float x) {
  float e = __expf(2.f * x);
  return 1.f - 2.f / (e + 1.f);
}

// Partial scores over one (DIM-half, K-slice):
// sp[b][half*4+ks][r] = sum_{d in half} tanh-free partial (pre-activation GEMM
// restricted to k in [ks*512, ks*512+512)) reduced with W3 AFTER tanh -- so the
// split must be on K only for the GEMM; tanh happens after combining K parts!
// => K-split partials must be PRE-tanh. We therefore store pre-activation
// c-partials reduced how? NO -- tanh is nonlinear. Instead: sp holds the
// pre-tanh GEMM partial? That is 64x256 per block, too big.
// Resolution: K-split the GEMM but keep tanh in one place: each (b,half,ks)
// block computes partial c (64x256) and ATOMICALLY accumulates? No.
// Simpler correct scheme used here: ks blocks write c-partials to ws and the
// LAST reducer applies tanh? Requires another pass.
// ACTUAL scheme: exploit associativity differently -- see below: we split K
// *inside* the block loop only; the grid K-split instead splits the N (col)
// dimension further: half in {0..7} of 64 cols each. Then tanh+W3 reduce stays
// local and partials are additive.
__global__ __launch_bounds__(512, 8) void score_k(const float* __restrict__ feat,
                                                  const ushort* __restrict__ wpack,
                                                  const float* __restrict__ pprime,
                                                  const float* __restrict__ W3,
                                                  float* __restrict__ sp) {
  // grid = B * 8 col-slices; block covers cols [slice*64, slice*64+64), K=2048.
  // 8 waves each own 64 rows x 8 cols?? -- cols per wave = 8 < 16 fragment min.
  // Instead: waves split K (8 waves x K=256 each), cols 64 per wave (ct=4,rt=4)
  // and partials are summed across waves via lds_part (pre-tanh c cannot be
  // summed across waves either!). => waves must NOT split K for the same col.
  // Final layout: 8 waves = 4 K-subslices x 2 col-subslices? same problem.
  //
  // Clean solution: block covers cols [slice*64,+64) with K=2048; the 8 waves
  // split K into 8 x 256; each wave's acc is a c-PARTIAL (pre-tanh), summed
  // across waves IN LDS (fp32 adds, linear!), then wave 0..? applies tanh+W3.
  // c-partial sharing: 64 rows x 64 cols x 4B = 16KB in LDS -- fits.
  int b = blockIdx.x >> 3;
  int slice = blockIdx.x & 7;          // 64-col slice of DIM
  int t = threadIdx.x;
  int wid = t >> 6;                    // wave = K-subslice of 256
  int l = t & 63;
  int l15 = l & 15, g = l >> 4;
  const float* featB = feat + (size_t)b * R_ * F_;

  __shared__ uint4 ldsA[2][512];       // 64 rows x 64 k bf16 (8KB), dbuf
  __shared__ float ldsC[R_][64 + 1];   // c accumulation 64x64 fp32 (+pad)
  __shared__ float lds_sc[R_];

  f32x4 acc[4][4];                     // rt x ct: 64 rows x 64 cols
  #pragma unroll
  for (int rt = 0; rt < 4; ++rt)
    #pragma unroll
    for (int ct = 0; ct < 4; ++ct)
      acc[rt][ct] = (f32x4){0.f, 0.f, 0.f, 0.f};

  // staging: 512 threads stage 64x64 fp32->bf16 tile (8 floats/thread)
  int row = t >> 3, kq = t & 7;
  // wave wid handles k in [wid*256, wid*256+256) => 4 K-steps of 64
  const float* rowp = featB + (size_t)row * F_ + kq * 8;

  { // prologue: stage K-tile 0 (k = [0,64) of k-step sequence below)
    const float4* src = reinterpret_cast<const float4*>(rowp);
    ldsA[0][kq * 64 + row] = pack8(src[0], src[1]);
  }

  // K-step sequence: step s covers global k [s*64, s*64+64), s = 0..31.
  // Wave wid computes on steps where (s>>2)==wid? NO -- every wave must hit
  // every barrier. All waves walk all 32 steps; wave wid only issues MFMAs on
  // its 4 steps [wid*4, wid*4+4). Staging is all-thread every step.
  for (int kt = 0; kt < 32; ++kt) {
    int cur = kt & 1;
    float4 a0, a1;
    if (kt < 31) {
      const float4* src = reinterpret_cast<const float4*>(rowp + (kt + 1) * 64);
      a0 = src[0]; a1 = src[1];
    }
    uint4 bfr[2][4];
    bool mywork = (kt >> 2) == wid;
    if (mywork) {
      #pragma unroll
      for (int s = 0; s < 2; ++s)
        #pragma unroll
        for (int ct = 0; ct < 4; ++ct) {
          int ctg = slice * 4 + ct;
          const ushort* wp = wpack + ((size_t)(kt * 2 + s) * 32 + (size_t)ctg) * 512 + (size_t)l * 8;
          bfr[s][ct] = *reinterpret_cast<const uint4*>(wp);
        }
    }

    __syncthreads();

    if (mywork) {
      bf16x8 af[2][4];
      #pragma unroll
      for (int s = 0; s < 2; ++s)
        #pragma unroll
        for (int rt = 0; rt < 4; ++rt)
          af[s][rt] = __builtin_bit_cast(bf16x8, ldsA[cur][(s * 4 + g) * 64 + rt * 16 + l15]);
      #pragma unroll
      for (int s = 0; s < 2; ++s)
        #pragma unroll
        for (int ct = 0; ct < 4; ++ct) {
          bf16x8 bv = __builtin_bit_cast(bf16x8, bfr[s][ct]);
          #pragma unroll
          for (int rt = 0; rt < 4; ++rt)
            acc[rt][ct] = __builtin_amdgcn_mfma_f32_16x16x32_bf16(af[s][rt], bv, acc[rt][ct], 0, 0, 0);
        }
    }

    if (kt < 31)
      ldsA[cur ^ 1][kq * 64 + row] = pack8(a0, a1);
  }

  // ---- cross-wave c reduction in LDS (pre-tanh, linear => additive) ----
  // zero ldsC, then atomic-free staged adds: wave w adds in order via barriers?
  // Cheaper: ldsC init from wave 0's acc, then 7 staged adds -> 7 barriers.
  // Cheapest: use atomicAdd on LDS (fp32) -- contention-free (distinct addrs
  // per lane within a wave; 8 waves may collide but HW handles it).
  // acc[rt][ct][j]: row = rt*16 + g*4 + j, col = ct*16 + l15.
  #pragma unroll
  for (int rt = 0; rt < 4; ++rt)
    #pragma unroll
    for (int ct = 0; ct < 4; ++ct)
      #pragma unroll
      for (int j = 0; j < 4; ++j) {
        int rr = rt * 16 + g * 4 + j;
        int cc = ct * 16 + l15;
        if (wid == 0) ldsC[rr][cc] = acc[rt][ct][j];
      }
  __syncthreads();
  #pragma unroll
  for (int rt = 0; rt < 4; ++rt)
    #pragma unroll
    for (int ct = 0; ct < 4; ++ct)
      #pragma unroll
      for (int j = 0; j < 4; ++j) {
        int rr = rt * 16 + g * 4 + j;
        int cc = ct * 16 + l15;
        if (wid != 0) atomicAdd(&ldsC[rr][cc], acc[rt][ct][j]);
      }
  __syncthreads();

  // ---- tanh + W3 dot: 512 threads cover 64 rows x 64 cols: t -> (row, 8 cols)
  {
    int rr = t >> 3;
    int c0 = (t & 7) * 8;
    int dbase = slice * 64 + c0;
    float v = 0.f;
    #pragma unroll
    for (int i = 0; i < 8; ++i) {
      int d = dbase + i;
      v += fast_tanh(ldsC[rr][c0 + i] + pprime[b * DIM_ + d]) * W3[d];
    }
    // reduce 8 threads (t&7) -> row sum; lanes t&7 consecutive in wave
    v += __shfl_xor(v, 1);
    v += __shfl_xor(v, 2);
    v += __shfl_xor(v, 4);
    if ((t & 7) == 0) lds_sc[rr] = v;
  }
  __syncthreads();
  if (t < R_)
    sp[((size_t)b * 8 + slice) * R_ + t] = lds_sc[t];
}

// softmax + weighted sum: grid = B*8, 256 thr, 256 f per block
__global__ __launch_bounds__(256) void wsum_k(const float* __restrict__ feat,
                                              const float* __restrict__ sp,
                                              float* __restrict__ out) {
  int b = blockIdx.x >> 3;
  int f0 = (blockIdx.x & 7) * 256;
  int t = threadIdx.x;
  __shared__ float lds_aw[R_];

  if (t < R_) {
    float s = 0.f;
    #pragma unroll
    for (int i = 0; i < 8; ++i) s += sp[((size_t)b * 8 + i) * R_ + t];
    float m = s;
    #pragma unroll
    for (int off = 32; off >= 1; off >>= 1) m = fmaxf(m, __shfl_xor(m, off));
    float e = __expf(s - m);
    float su = e;
    #pragma unroll
    for (int off = 32; off >= 1; off >>= 1) su += __shfl_xor(su, off);
    lds_aw[t] = e / su;
  }
  __syncthreads();

  const float* fp = feat + (size_t)b * R_ * F_ + f0 + t;
  float qa = 0.f;
  #pragma unroll 8
  for (int r = 0; r < R_; ++r)
    qa += lds_aw[r] * fp[(size_t)r * F_];
  out[(size_t)b * F_ + f0 + t] = qa;
}

extern "C" void kernel_launch(void* const* d_in, const int* in_sizes, int n_in,
                              void* d_out, int out_size, void* d_ws, size_t ws_size,
                              hipStream_t stream) {
  const float* feat = (const float*)d_in[0];   // [B,R,F]
  const float* prev = (const float*)d_in[1];   // [B,H]
  const float* Ww   = (const float*)d_in[2];   // [F,DIM]
  const float* Wb   = (const float*)d_in[3];   // [DIM]
  const float* W2w  = (const float*)d_in[4];   // [H,DIM]
  const float* W2b  = (const float*)d_in[5];   // [DIM]
  const float* W3w  = (const float*)d_in[6];   // [DIM,1]
  // d_in[7] = W3_b: cancels in softmax
  float* out = (float*)d_out;

  ushort* wpack  = (ushort*)d_ws;                                          // 2 MB
  float*  pprime = (float*)((char*)d_ws + (size_t)F_ * DIM_ * 2);          // 512 KB
  float*  sp     = (float*)((char*)d_ws + (size_t)F_ * DIM_ * 2
                                        + (size_t)B_ * DIM_ * 4);          // 512 KB

  pack_w_k<<<(F_ * DIM_) / 256, 256, 0, stream>>>(Ww, wpack);
  prep_p_k<<<256, 256, 0, stream>>>(prev, W2w, W2b, Wb, pprime);
  score_k<<<B_ * 8, 512, 0, stream>>>(feat, wpack, pprime, W3w, sp);
  wsum_k<<<B_ * 8, 256, 0, stream>>>(feat, sp, out);
}

// Round 4
// 132.942 us; speedup vs baseline: 8.4085x; 8.4085x over previous
//
#include <hip/hip_runtime.h>
#include <hip/hip_bf16.h>

// attention_84464826843938: additive-attention pooling, MI355X (gfx950)
//
// R4: fix barrier-drain convoy + XCD-colocated N-split.
//  - R2 postmortem: globals issued immediately before __syncthreads -> compiler
//    s_waitcnt vmcnt(0) drain exposes full latency EVERY K-step (6200 cyc/step).
//  - R3 postmortem: consecutive-blockIdx slices of one b land on different XCDs
//    -> 8x HBM fetch. Fix: slice-major index (all slices of b on same XCD).
//  K3 score_k: grid = 4 slices x 256 b (slice-major), 256 thr / 4 waves,
//    wave = 64 rows x 32 cols, BN=128. Per K-step: one barrier; prefetches
//    (A kt+2, B kt+1) issued AFTER the barrier so they are ~1 step old at the
//    next drain. A staged fp32->bf16 in XOR-swizzled LDS chunks (dbuf).
//  K4 wsum_k: softmax over 4 partials + weighted feature sum.

#define B_ 256
#define R_ 64
#define F_ 2048
#define H_ 512
#define DIM_ 512

typedef short bf16x8 __attribute__((ext_vector_type(8)));
typedef float f32x4 __attribute__((ext_vector_type(4)));

__device__ __forceinline__ ushort f2bf(float x) {
  __hip_bfloat16 h = __float2bfloat16(x);
  return __builtin_bit_cast(ushort, h);
}

__device__ __forceinline__ uint4 pack8(float4 x, float4 y) {
  uint4 r;
  r.x = (uint)f2bf(x.x) | ((uint)f2bf(x.y) << 16);
  r.y = (uint)f2bf(x.z) | ((uint)f2bf(x.w) << 16);
  r.z = (uint)f2bf(y.x) | ((uint)f2bf(y.y) << 16);
  r.w = (uint)f2bf(y.z) | ((uint)f2bf(y.w) << 16);
  return r;
}

// wpack[((kt32*32 + ctg)*64 + g*16 + c)*8 + i] = bf16(W_w[kt32*32 + g*8 + i][ctg*16 + c])
__global__ void pack_w_k(const float* __restrict__ Ww, ushort* __restrict__ wpack) {
  int idx = blockIdx.x * 256 + threadIdx.x;
  float v = Ww[idx];
  int k = idx >> 9;
  int d = idx & 511;
  int kt = k >> 5, kr = k & 31;
  int g = kr >> 3, i = kr & 7;
  int ctg = d >> 4, c = d & 15;
  size_t dst = ((size_t)((kt * 32 + ctg) * 64 + g * 16 + c)) * 8 + (size_t)i;
  wpack[dst] = f2bf(v);
}

// p'[b][d] = prev[b]@W2_w[:,d] + W2_b[d] + W_b[d]
__global__ __launch_bounds__(256) void prep_p_k(const float* __restrict__ prev,
                                                const float* __restrict__ W2w,
                                                const float* __restrict__ W2b,
                                                const float* __restrict__ Wb,
                                                float* __restrict__ pprime) {
  __shared__ float lprev[8][H_];
  int bg = blockIdx.x >> 3;
  int d0 = (blockIdx.x & 7) * 64;
  int t = threadIdx.x;
  const float4* src = reinterpret_cast<const float4*>(prev + (size_t)bg * 8 * H_);
  float4* dst = reinterpret_cast<float4*>(&lprev[0][0]);
  for (int i = t; i < 8 * H_ / 4; i += 256) dst[i] = src[i];
  __syncthreads();
  int d = d0 + (t & 63);
  int bq = t >> 6;
  float a0 = 0.f, a1 = 0.f;
  #pragma unroll 8
  for (int h = 0; h < H_; ++h) {
    float wv = W2w[h * DIM_ + d];
    a0 += lprev[bq][h] * wv;
    a1 += lprev[bq + 4][h] * wv;
  }
  float bias = W2b[d] + Wb[d];
  pprime[(size_t)(bg * 8 + bq) * DIM_ + d] = a0 + bias;
  pprime[(size_t)(bg * 8 + bq + 4) * DIM_ + d] = a1 + bias;
}

__device__ __forceinline__ float fast_tanh(float x) {
  float e = __expf(2.f * x);
  return 1.f - 2.f / (e + 1.f);
}

// sp[b*4+slice][r] = sum_{d in slice's 128 cols} tanh(c[b][r][d]+p'[b][d])*W3[d]
__global__ __launch_bounds__(256, 4) void score_k(const float* __restrict__ feat,
                                                  const ushort* __restrict__ wpack,
                                                  const float* __restrict__ pprime,
                                                  const float* __restrict__ W3,
                                                  float* __restrict__ sp) {
  int slice = blockIdx.x >> 8;         // slice-major: all slices of b -> same XCD
  int b = blockIdx.x & 255;
  int t = threadIdx.x;
  int wid = t >> 6;                    // 4 waves; wave owns cols [wid*32, +32)
  int l = t & 63;
  int l15 = l & 15, g = l >> 4;
  const float* featB = feat + (size_t)b * R_ * F_;

  // A tile: 64 rows x 64 k bf16 as 16B chunks; chunk(kc,row) at index
  // kc*64 + (row ^ (kc&7))  [XOR-swizzle: fixes 4/8-way write conflicts]
  __shared__ uint4 ldsA[2][512];       // 2 x 8 KB
  __shared__ float lds_part[4][R_];

  f32x4 acc[4][2];
  #pragma unroll
  for (int rt = 0; rt < 4; ++rt)
    #pragma unroll
    for (int ct = 0; ct < 2; ++ct)
      acc[rt][ct] = (f32x4){0.f, 0.f, 0.f, 0.f};

  int row = t >> 2, kq = t & 3;        // staging: 16 floats of one row / thread
  const float* rowp = featB + (size_t)row * F_ + kq * 16;
  int kc0 = kq * 2, kc1 = kq * 2 + 1;
  int wr0 = kc0 * 64 + (row ^ (kc0 & 7));
  int wr1 = kc1 * 64 + (row ^ (kc1 & 7));

  { // prologue: stage tile 0
    const float4* s0 = reinterpret_cast<const float4*>(rowp);
    float4 p0 = s0[0], p1 = s0[1], p2 = s0[2], p3 = s0[3];
    ldsA[0][wr0] = pack8(p0, p1);
    ldsA[0][wr1] = pack8(p2, p3);
  }
  // prefetch A(1) to regs
  float4 a0, a1, a2, a3;
  {
    const float4* s1 = reinterpret_cast<const float4*>(rowp + 64);
    a0 = s1[0]; a1 = s1[1]; a2 = s1[2]; a3 = s1[3];
  }
  // prefetch B(0) frags
  uint4 bfr[2][2];
  #pragma unroll
  for (int s = 0; s < 2; ++s)
    #pragma unroll
    for (int ct = 0; ct < 2; ++ct) {
      int ctg = slice * 8 + wid * 2 + ct;
      bfr[s][ct] = *reinterpret_cast<const uint4*>(
          wpack + ((size_t)(0 * 2 + s) * 32 + (size_t)ctg) * 512 + (size_t)l * 8);
    }

  for (int kt = 0; kt < 32; ++kt) {
    int cur = kt & 1;
    __syncthreads();                   // tile kt visible; drains ~1-step-old globals

    // write tile kt+1 (regs loaded last iter -> already drained by barrier)
    if (kt < 31) {
      ldsA[cur ^ 1][wr0] = pack8(a0, a1);
      ldsA[cur ^ 1][wr1] = pack8(a2, a3);
    }
    // issue A(kt+2): a full step in flight before next drain
    if (kt < 30) {
      const float4* sn = reinterpret_cast<const float4*>(rowp + (kt + 2) * 64);
      a0 = sn[0]; a1 = sn[1]; a2 = sn[2]; a3 = sn[3];
    }
    // issue B(kt+1)
    uint4 bfr2[2][2];
    if (kt < 31) {
      #pragma unroll
      for (int s = 0; s < 2; ++s)
        #pragma unroll
        for (int ct = 0; ct < 2; ++ct) {
          int ctg = slice * 8 + wid * 2 + ct;
          bfr2[s][ct] = *reinterpret_cast<const uint4*>(
              wpack + ((size_t)((kt + 1) * 2 + s) * 32 + (size_t)ctg) * 512 + (size_t)l * 8);
        }
    }

    bf16x8 af[2][4];
    #pragma unroll
    for (int s = 0; s < 2; ++s)
      #pragma unroll
      for (int rt = 0; rt < 4; ++rt) {
        int kc = s * 4 + g;
        af[s][rt] = __builtin_bit_cast(bf16x8,
            ldsA[cur][kc * 64 + ((rt * 16 + l15) ^ (kc & 7))]);
      }

    #pragma unroll
    for (int s = 0; s < 2; ++s)
      #pragma unroll
      for (int ct = 0; ct < 2; ++ct) {
        bf16x8 bv = __builtin_bit_cast(bf16x8, bfr[s][ct]);
        #pragma unroll
        for (int rt = 0; rt < 4; ++rt)
          acc[rt][ct] = __builtin_amdgcn_mfma_f32_16x16x32_bf16(af[s][rt], bv, acc[rt][ct], 0, 0, 0);
      }

    #pragma unroll
    for (int s = 0; s < 2; ++s)
      #pragma unroll
      for (int ct = 0; ct < 2; ++ct)
        bfr[s][ct] = bfr2[s][ct];
  }

  // epilogue: tanh + W3 dot, in registers
  // acc[rt][ct][j] = c[row = rt*16 + g*4 + j][col = slice*128 + wid*32 + ct*16 + l15]
  float pp[2], w3v[2];
  #pragma unroll
  for (int ct = 0; ct < 2; ++ct) {
    int col = slice * 128 + wid * 32 + ct * 16 + l15;
    pp[ct] = pprime[b * DIM_ + col];
    w3v[ct] = W3[col];
  }
  #pragma unroll
  for (int rt = 0; rt < 4; ++rt) {
    #pragma unroll
    for (int j = 0; j < 4; ++j) {
      float v = fast_tanh(acc[rt][0][j] + pp[0]) * w3v[0]
              + fast_tanh(acc[rt][1][j] + pp[1]) * w3v[1];
      v += __shfl_xor(v, 1);
      v += __shfl_xor(v, 2);
      v += __shfl_xor(v, 4);
      v += __shfl_xor(v, 8);
      if (l15 == 0) lds_part[wid][rt * 16 + g * 4 + j] = v;
    }
  }
  __syncthreads();

  if (t < R_) {
    float s = lds_part[0][t] + lds_part[1][t] + lds_part[2][t] + lds_part[3][t];
    sp[((size_t)b * 4 + slice) * R_ + t] = s;
  }
}

// softmax + weighted sum: grid = B*4, 256 thr, 512 f per block
__global__ __launch_bounds__(256) void wsum_k(const float* __restrict__ feat,
                                              const float* __restrict__ sp,
                                              float* __restrict__ out) {
  int b = blockIdx.x >> 2;
  int f0 = (blockIdx.x & 3) * 512;
  int t = threadIdx.x;
  __shared__ float lds_aw[R_];

  if (t < R_) {
    float s = sp[((size_t)b * 4 + 0) * R_ + t] + sp[((size_t)b * 4 + 1) * R_ + t]
            + sp[((size_t)b * 4 + 2) * R_ + t] + sp[((size_t)b * 4 + 3) * R_ + t];
    float m = s;
    #pragma unroll
    for (int off = 32; off >= 1; off >>= 1) m = fmaxf(m, __shfl_xor(m, off));
    float e = __expf(s - m);
    float su = e;
    #pragma unroll
    for (int off = 32; off >= 1; off >>= 1) su += __shfl_xor(su, off);
    lds_aw[t] = e / su;
  }
  __syncthreads();

  const float* fp = feat + (size_t)b * R_ * F_ + f0 + t * 2;
  float qx = 0.f, qy = 0.f;
  #pragma unroll 8
  for (int r = 0; r < R_; ++r) {
    float a = lds_aw[r];
    float2 v = *reinterpret_cast<const float2*>(fp + (size_t)r * F_);
    qx += a * v.x;
    qy += a * v.y;
  }
  *reinterpret_cast<float2*>(out + (size_t)b * F_ + f0 + t * 2) = (float2){qx, qy};
}

extern "C" void kernel_launch(void* const* d_in, const int* in_sizes, int n_in,
                              void* d_out, int out_size, void* d_ws, size_t ws_size,
                              hipStream_t stream) {
  const float* feat = (const float*)d_in[0];   // [B,R,F]
  const float* prev = (const float*)d_in[1];   // [B,H]
  const float* Ww   = (const float*)d_in[2];   // [F,DIM]
  const float* Wb   = (const float*)d_in[3];   // [DIM]
  const float* W2w  = (const float*)d_in[4];   // [H,DIM]
  const float* W2b  = (const float*)d_in[5];   // [DIM]
  const float* W3w  = (const float*)d_in[6];   // [DIM,1]
  // d_in[7] = W3_b: cancels in softmax
  float* out = (float*)d_out;

  ushort* wpack  = (ushort*)d_ws;                                          // 2 MB
  float*  pprime = (float*)((char*)d_ws + (size_t)F_ * DIM_ * 2);          // 512 KB
  float*  sp     = (float*)((char*)d_ws + (size_t)F_ * DIM_ * 2
                                        + (size_t)B_ * DIM_ * 4);          // 256 KB

  pack_w_k<<<(F_ * DIM_) / 256, 256, 0, stream>>>(Ww, wpack);
  prep_p_k<<<256, 256, 0, stream>>>(prev, W2w, W2b, Wb, pprime);
  score_k<<<B_ * 4, 256, 0, stream>>>(feat, wpack, pprime, W3w, sp);
  wsum_k<<<B_ * 4, 256, 0, stream>>>(feat, sp, out);
}